// Round 11
// baseline (194.289 us; speedup 1.0000x reference)
//
#include <hip/hip_runtime.h>
#include <stdint.h>

#define H_ 96
#define W_ 96
#define C_ 256
#define O_ 256
#define N_ 2
#define HW_ (H_*W_)          // 9216
#define M_ (N_*HW_)          // 18432
#define GK 2304              // C_*9

typedef _Float16 f16x8 __attribute__((ext_vector_type(8)));
typedef _Float16 f16x2 __attribute__((ext_vector_type(2)));
typedef float f32x4 __attribute__((ext_vector_type(4)));
typedef unsigned short us4 __attribute__((ext_vector_type(4)));
typedef unsigned short us8 __attribute__((ext_vector_type(8)));

__device__ __forceinline__ unsigned short f2h(float f) {
  union { _Float16 h; unsigned short u; } v;
  v.h = (_Float16)f;
  return v.u;
}
__device__ __forceinline__ f16x2 hpair(float f) {
  const _Float16 h = (_Float16)f;
  return (f16x2){h, h};
}

// ---------------- Kernel 1: combined prep (fp16), unchanged.
__global__ __launch_bounds__(256) void k_pre(const float* __restrict__ x,
                                             const float* __restrict__ w_df,
                                             const float* __restrict__ w_tm,
                                             const float* __restrict__ w_tr,
                                             unsigned short* __restrict__ xt,
                                             unsigned short* __restrict__ wfrag,
                                             unsigned short* __restrict__ w6p) {
  const int b = blockIdx.x;
  const int tid = threadIdx.x;
  if (b < 576) {
    __shared__ unsigned short tile[64][130];
    const int pt = b % 144;          // 144 p-tiles of 64
    const int ch = (b / 144) & 1;    // 2 c-halves of 128
    const int n  = b / 288;
    const int p0 = pt * 64, c0 = ch * 128;
    const float* xp = x + (size_t)n * C_ * HW_;
    unsigned short* xtp = xt + (size_t)n * C_ * HW_;
    const int tx = tid & 15, ty = tid >> 4;  // 16 p-chunks x 16 c-rows
#pragma unroll
    for (int pass = 0; pass < 8; pass++) {
      const int c = pass * 16 + ty;
      const f32x4 v = *(const f32x4*)(xp + (size_t)(c0 + c) * HW_ + p0 + tx * 4);
#pragma unroll
      for (int i = 0; i < 4; i++) tile[tx * 4 + i][c] = f2h(v[i]);
    }
    __syncthreads();
    const int l32 = tid & 31, pr = tid >> 5;  // 32 c-chunks x 8 p-rows
#pragma unroll
    for (int pass = 0; pass < 8; pass++) {
      const int p = pass * 8 + pr;
      us4 v;
#pragma unroll
      for (int i = 0; i < 4; i++) v[i] = tile[p][l32 * 4 + i];
      *(us4*)(xtp + (size_t)(p0 + p) * C_ + c0 + l32 * 4) = v;
    }
  } else if (b < 864) {
    const int base = (b - 576) * 2048 + tid * 8;  // < 589824
    const int l  = (base >> 3) & 63;
    const int g  = (base >> 9) & 15;
    const int ks = (base >> 13) & 7;
    const int t  = base >> 16;
    const int o  = g * 16 + (l & 15);
    const int c  = ks * 32 + (l >> 4) * 8;
    us8 res;
#pragma unroll
    for (int j = 0; j < 8; j++) res[j] = f2h(w_df[(size_t)(o * 256 + c + j) * 9 + t]);
    *(us8*)(wfrag + base) = res;
  } else {
    int idx = (b - 864) * 256 + tid;   // < 9*16*256 = 36864
    int t = idx >> 12;
    int r = idx & 4095;
    int j = r >> 8;
    int c = r & 255;
    float v = 0.f;
    if (j < 4) v = w_tm[(size_t)(j * C_ + c) * 9 + t];
    else if (j < 6) v = w_tr[(size_t)((j - 4) * C_ + c) * 9 + t];
    w6p[idx] = f2h(v);
  }
}

// ---------------- Kernel 2: FUSED offsets + sample + GEMM + BN + res + ReLU.
// v13 = v12 geometry (grid 256, 1 block/CU, fat80/thin64, same bytes) with
// 1024 THREADS / 16 WAVES: 4 waves/SIMD (was 2). v11 dropped below the
// per-CU byte wall (17.8 < 23-31 B/cyc), so exposed latency binds and
// latency-hiding capacity is the lever -- but bytes must not grow (v4/v8).
//  - m-split: waves 0-7 own tiles 0..2, waves 8-15 own tiles 3..4 (thin:
//    2/2), each wave keeps the 32-o range. LDS read traffic per CU is
//    UNCHANGED (16 waves x 2.5 = 8 x 5); B unique bytes unchanged (second
//    m-half re-reads the same frags -> L1 hits).
//  - staging: 64 rows/pass (1 row/thread); fat's 16 extra rows = short
//    serial chain on waves 0-3 only. Cross-tap corner prefetch kept.
//  - B rolling prefetch depth-2 (4 frags; load ks+2 at step ks).
//  - VGPR ~110-120 vs the hard 128 cap of 16-wave blocks (512/SIMD / 4).
//    Tripwire: WRITE_SIZE must stay ~18.4-18.7MB (no spill).
__global__ __launch_bounds__(1024) void k_fused(const unsigned short* __restrict__ xt,
                                                const unsigned short* __restrict__ Wfrag,
                                                const unsigned short* __restrict__ w6p,
                                                const float* __restrict__ b_tm,
                                                const float* __restrict__ b_tr,
                                                const float* __restrict__ xres,
                                                const float* __restrict__ gamma,
                                                const float* __restrict__ beta,
                                                const float* __restrict__ mean,
                                                const float* __restrict__ var,
                                                float* __restrict__ out) {
  __shared__ unsigned short As[2][80 * 256] __attribute__((aligned(16)));  // 80KB
  __shared__ float sred5[5][8][16][8];     // 20.5KB (prologue only)
  __shared__ float coords_s[80][9][2];     // 5.76KB
  __shared__ int   nofs[80];               // per-row xt element offset (n*C*HW)
  const int tid = threadIdx.x;
  const int wave = tid >> 6, lane = tid & 63;
  const int w7 = wave & 7, half = wave >> 3;
  const int row = lane & 15, quad = lane >> 4;
  // XCD-clustered bijective map: 256 blocks -> pb 0..255, 32 per XCD.
  const int pb = (blockIdx.x & 7) * 32 + (blockIdx.x >> 3);
  const bool fat = pb < 128;
  const int nt = fat ? 5 : 4;              // 16-row tiles in this block
  const int m0 = fat ? pb * 80 : 10240 + (pb - 128) * 64;
  // GEMM m-split: this wave's tile base and count
  const int tb  = half ? (fat ? 3 : 2) : 0;
  const int ntw = half ? 2 : (fat ? 3 : 2);
  const int sr = tid >> 4;  // staging row 0..63 (one row per thread)
  const int cg = tid & 15;  // staging 16-channel group

  // ---- Prologue: offset conv, per 16-row tile; tile parity by wave-half ----
#pragma unroll
  for (int t5 = 0; t5 < 5; ++t5) {
    if (t5 < nt && (t5 & 1) == half) {
      const int ts = m0 + t5 * 16;
      const int nn = ts / HW_;
      const int hw = ts - nn * HW_;
      const int h = hw / W_, w0 = hw - h * W_;  // w0 multiple of 16
      const unsigned short* xts = xt + (size_t)nn * C_ * HW_;
      const int cq = w7 * 32;   // 8 waves/group x 32ch = full K per tap
      f32x4 oacc = {0.f, 0.f, 0.f, 0.f};
      const f16x8 zero8 = {};
#pragma unroll
      for (int t = 0; t < 9; t++) {
        const int ty = t / 3, tx = t % 3;
        const int y = h + ty - 1;
        if (y < 0 || y >= H_) continue;  // tile-uniform
        const int xx = w0 + row + tx - 1;
        const bool valid = (xx >= 0) && (xx < W_);
        const int xc = min(max(xx, 0), W_ - 1);
        f16x8 av = *(const f16x8*)(const void*)(xts + (size_t)(y * W_ + xc) * C_ + cq + quad * 8);
        if (!valid) av = zero8;
        const f16x8 bv = *(const f16x8*)(const void*)(w6p + (size_t)(t * 16 + row) * C_ + cq + quad * 8);
        oacc = __builtin_amdgcn_mfma_f32_16x16x32_f16(av, bv, oacc, 0, 0, 0);
      }
      if (row < 6) {
#pragma unroll
        for (int r = 0; r < 4; r++) sred5[t5][w7][quad * 4 + r][row] = oacc[r];
      }
    }
  }
  __syncthreads();
  if (tid < nt * 16) {
    const int rg = tid;                 // row in block
    const int gm = m0 + rg;
    const int nn = gm / HW_;
    const int hw = gm - nn * HW_;
    const int h = hw / W_, w = hw - h * W_;
    const int tt = rg >> 4, mm = rg & 15;
    float a[6];
#pragma unroll
    for (int j = 0; j < 6; j++) {
      float s = 0.f;
#pragma unroll
      for (int wv = 0; wv < 8; wv++) s += sred5[tt][wv][mm][j];
      a[j] = s;
    }
    const float tm0 = a[0] + b_tm[0];
    const float tm1 = a[1] + b_tm[1];
    const float tm2 = a[2] + b_tm[2];
    const float tm3 = a[3] + b_tm[3];
    const float tr0 = a[4] + b_tr[0];
    const float tr1 = a[5] + b_tr[1];
#pragma unroll
    for (int t = 0; t < 9; t++) {
      const float ry = (float)(t / 3) - 1.f;
      const float rx = (float)(t % 3) - 1.f;
      coords_s[rg][t][0] = (float)h + tr0 + tm0 * ry + tm1 * rx;
      coords_s[rg][t][1] = (float)w + tr1 + tm2 * ry + tm3 * rx;
    }
    nofs[rg] = nn * (C_ * HW_);
  }
  __syncthreads();

  // ---- Main loop over 9 taps, pipelined staging ----
  f32x4 acc[3][2] = {};   // [m-tile within wave][o-frag]
  float cwA[4];
  us8 uA0[4], uA1[4];     // one corner register set

  // compute weights + issue 8 corner loads for row R of tap TAP
#define ISSUE(R, TAP)                                                          \
  {                                                                            \
    const int r_ = (R);                                                        \
    const int nof = nofs[r_];                                                  \
    const float py = coords_s[r_][TAP][0];                                     \
    const float px = coords_s[r_][TAP][1];                                     \
    const float fy = floorf(py), fx = floorf(px);                              \
    const float wy = py - fy, wx = px - fx;                                    \
    const int y0 = (int)fy, x0 = (int)fx;                                      \
    const int y1 = y0 + 1, x1 = x0 + 1;                                        \
    const float vy0 = (y0 >= 0 && y0 < H_) ? 1.f : 0.f;                        \
    const float vy1 = (y1 >= 0 && y1 < H_) ? 1.f : 0.f;                        \
    const float vx0 = (x0 >= 0 && x0 < W_) ? 1.f : 0.f;                        \
    const float vx1 = (x1 >= 0 && x1 < W_) ? 1.f : 0.f;                        \
    cwA[0] = (1.f - wy) * (1.f - wx) * vy0 * vx0;                              \
    cwA[1] = (1.f - wy) * wx * vy0 * vx1;                                      \
    cwA[2] = wy * (1.f - wx) * vy1 * vx0;                                      \
    cwA[3] = wy * wx * vy1 * vx1;                                              \
    const int cy0 = min(max(y0, 0), H_ - 1), cy1 = min(max(y1, 0), H_ - 1);    \
    const int cx0 = min(max(x0, 0), W_ - 1), cx1 = min(max(x1, 0), W_ - 1);    \
    const int b0 = nof + (cy0 * W_ + cx0) * C_ + cg * 16;                      \
    const int b1 = nof + (cy0 * W_ + cx1) * C_ + cg * 16;                      \
    const int b2 = nof + (cy1 * W_ + cx0) * C_ + cg * 16;                      \
    const int b3 = nof + (cy1 * W_ + cx1) * C_ + cg * 16;                      \
    uA0[0] = *(const us8*)(xt + b0); uA1[0] = *(const us8*)(xt + b0 + 8);      \
    uA0[1] = *(const us8*)(xt + b1); uA1[1] = *(const us8*)(xt + b1 + 8);      \
    uA0[2] = *(const us8*)(xt + b2); uA1[2] = *(const us8*)(xt + b2 + 8);      \
    uA0[3] = *(const us8*)(xt + b3); uA1[3] = *(const us8*)(xt + b3 + 8);      \
  }

  // lerp the set and write row R into ASB (swizzled slot=(q&24)|((q^R)&7))
#define LERPW(R, ASB)                                                          \
  {                                                                            \
    const int r_ = (R);                                                        \
    const f16x2 c0 = hpair(cwA[0]), c1 = hpair(cwA[1]);                        \
    const f16x2 c2 = hpair(cwA[2]), c3 = hpair(cwA[3]);                        \
    us8 r0v, r1v;                                                              \
    {                                                                          \
      const f16x2* p0 = (const f16x2*)&uA0[0];                                 \
      const f16x2* p1 = (const f16x2*)&uA0[1];                                 \
      const f16x2* p2 = (const f16x2*)&uA0[2];                                 \
      const f16x2* p3 = (const f16x2*)&uA0[3];                                 \
      f16x2* d = (f16x2*)&r0v;                                                 \
      _Pragma("unroll")                                                        \
      for (int p = 0; p < 4; p++) {                                            \
        f16x2 r = p0[p] * c0; r = p1[p] * c1 + r;                              \
        r = p2[p] * c2 + r;   r = p3[p] * c3 + r;  d[p] = r;                   \
      }                                                                        \
    }                                                                          \
    {                                                                          \
      const f16x2* p0 = (const f16x2*)&uA1[0];                                 \
      const f16x2* p1 = (const f16x2*)&uA1[1];                                 \
      const f16x2* p2 = (const f16x2*)&uA1[2];                                 \
      const f16x2* p3 = (const f16x2*)&uA1[3];                                 \
      f16x2* d = (f16x2*)&r1v;                                                 \
      _Pragma("unroll")                                                        \
      for (int p = 0; p < 4; p++) {                                            \
        f16x2 r = p0[p] * c0; r = p1[p] * c1 + r;                              \
        r = p2[p] * c2 + r;   r = p3[p] * c3 + r;  d[p] = r;                   \
      }                                                                        \
    }                                                                          \
    const int q0i = cg * 2, q1i = cg * 2 + 1;                                  \
    const int s0 = (q0i & 24) | ((q0i ^ r_) & 7);                              \
    const int s1 = (q1i & 24) | ((q1i ^ r_) & 7);                              \
    *(us8*)(void*)&ASB[r_ * 256 + s0 * 8] = r0v;                               \
    *(us8*)(void*)&ASB[r_ * 256 + s1 * 8] = r1v;                               \
  }

  // One GEMM step: MFMAs with pair (BX,BY); load pair for KS+2 into them.
#define GS(KS, BX, BY)                                                         \
  {                                                                            \
    const int q = (KS) * 4 + quad;                                             \
    const int slot = (q & 24) | ((q ^ row) & 7);                               \
    f16x8 a0 = *(const f16x8*)(const void*)&asb[((tb + 0) * 16 + row) * 256 + slot * 8]; \
    f16x8 a1 = *(const f16x8*)(const void*)&asb[((tb + 1) * 16 + row) * 256 + slot * 8]; \
    f16x8 a2;                                                                  \
    if (ntw > 2) a2 = *(const f16x8*)(const void*)&asb[((tb + 2) * 16 + row) * 256 + slot * 8]; \
    f16x8 nx, ny;                                                              \
    if ((KS) < 6) {                                                            \
      const unsigned short* wfn = wfTap + (size_t)((KS) + 2) * 8192;           \
      nx = *(const f16x8*)(const void*)(wfn);                                  \
      ny = *(const f16x8*)(const void*)(wfn + 512);                            \
    }                                                                          \
    acc[0][0] = __builtin_amdgcn_mfma_f32_16x16x32_f16(a0, BX, acc[0][0], 0, 0, 0); \
    acc[0][1] = __builtin_amdgcn_mfma_f32_16x16x32_f16(a0, BY, acc[0][1], 0, 0, 0); \
    acc[1][0] = __builtin_amdgcn_mfma_f32_16x16x32_f16(a1, BX, acc[1][0], 0, 0, 0); \
    acc[1][1] = __builtin_amdgcn_mfma_f32_16x16x32_f16(a1, BY, acc[1][1], 0, 0, 0); \
    if (ntw > 2) {                                                             \
      acc[2][0] = __builtin_amdgcn_mfma_f32_16x16x32_f16(a2, BX, acc[2][0], 0, 0, 0); \
      acc[2][1] = __builtin_amdgcn_mfma_f32_16x16x32_f16(a2, BY, acc[2][1], 0, 0, 0); \
    }                                                                          \
    if ((KS) < 6) { BX = nx; BY = ny; }                                        \
  }

  const bool third = fat && (sr < 16);  // wave-uniform (waves 0-3)

  // prime the pipeline: corners for (sr, tap 0)
  ISSUE(sr, 0);
  __builtin_amdgcn_sched_barrier(0);

  for (int tap = 0; tap < 9; tap++) {
    unsigned short* __restrict__ asb = &As[tap & 1][0];
    const unsigned short* wfTap =
        Wfrag + (size_t)tap * 65536 + w7 * 1024 + lane * 8;

    // B pairs for ks0,ks1 issued pre-lerp: latency hides under lerp VALU,
    // completed by the barrier's vmcnt drain.
    f16x8 B0 = *(const f16x8*)(const void*)(wfTap);
    f16x8 B1 = *(const f16x8*)(const void*)(wfTap + 512);
    f16x8 B2 = *(const f16x8*)(const void*)(wfTap + 8192);
    f16x8 B3 = *(const f16x8*)(const void*)(wfTap + 8704);
    __builtin_amdgcn_sched_barrier(0);

    LERPW(sr, asb);
    if (third) {            // fat extra rows 64..79: short serial chain
      ISSUE(sr + 64, tap);
      __builtin_amdgcn_sched_barrier(0);
      LERPW(sr + 64, asb);
    }

    __syncthreads();  // ONE barrier per tap (drains all pre-barrier loads)

    if (tap < 8) {    // cross-tap prefetch: hidden under the whole ks loop
      ISSUE(sr, tap + 1);
      __builtin_amdgcn_sched_barrier(0);
    }

    GS(0, B0, B1)
    GS(1, B2, B3)
    GS(2, B0, B1)
    GS(3, B2, B3)
    GS(4, B0, B1)
    GS(5, B2, B3)
    GS(6, B0, B1)
    GS(7, B2, B3)
    // NO trailing barrier: As double-buffered; next write to As[tap&1]
    // happens after barrier(tap+1), which orders all reads of As[tap&1].
  }

  // ---- Epilogue: BN + residual + ReLU, this wave's tiles x 32-o range ----
#pragma unroll
  for (int ot = 0; ot < 2; ot++) {
    const int o = w7 * 32 + ot * 16 + row;
    const float sc = rsqrtf(var[o] + 1e-5f) * gamma[o];
    const float bi = beta[o] - mean[o] * sc;
#pragma unroll
    for (int i = 0; i < 3; i++) {
      if (i < ntw) {
        const int t5 = tb + i;
        const int ts = m0 + t5 * 16;
        const int nn = ts / HW_;
        const int hw0 = ts - nn * HW_ + quad * 4;
        const size_t ob = (size_t)(nn * O_ + o) * HW_ + hw0;
        const f32x4 rv = *(const f32x4*)(xres + ob);
        f32x4 ov;
#pragma unroll
        for (int r = 0; r < 4; r++) ov[r] = fmaxf(acc[i][ot][r] * sc + bi + rv[r], 0.f);
        *(f32x4*)(out + ob) = ov;
      }
    }
  }
}

extern "C" void kernel_launch(void* const* d_in, const int* in_sizes, int n_in,
                              void* d_out, int out_size, void* d_ws, size_t ws_size,
                              hipStream_t stream) {
  const float* x     = (const float*)d_in[0];
  const float* w_tm  = (const float*)d_in[2];
  const float* b_tm  = (const float*)d_in[3];
  const float* w_tr  = (const float*)d_in[4];
  const float* b_tr  = (const float*)d_in[5];
  const float* w_df  = (const float*)d_in[6];
  const float* gamma = (const float*)d_in[7];
  const float* beta  = (const float*)d_in[8];
  const float* mean  = (const float*)d_in[9];
  const float* var   = (const float*)d_in[10];
  float* out = (float*)d_out;

  char* ws = (char*)d_ws;
  unsigned short* xt    = (unsigned short*)(ws);                       //  9,437,184 B
  unsigned short* wfrag = (unsigned short*)(ws + 9437184);             //  1,179,648 B
  unsigned short* w6p   = (unsigned short*)(ws + 9437184 + 1179648);   //     73,728 B

  k_pre<<<1008, 256, 0, stream>>>(x, w_df, w_tm, w_tr, xt, wfrag, w6p);
  k_fused<<<256, 1024, 0, stream>>>(xt, wfrag, w6p, b_tm, b_tr, x,
                                    gamma, beta, mean, var, out);
}

// Round 12
// 193.694 us; speedup vs baseline: 1.0031x; 1.0031x over previous
//
#include <hip/hip_runtime.h>
#include <stdint.h>

#define H_ 96
#define W_ 96
#define C_ 256
#define O_ 256
#define N_ 2
#define HW_ (H_*W_)          // 9216
#define M_ (N_*HW_)          // 18432
#define GK 2304              // C_*9

typedef _Float16 f16x8 __attribute__((ext_vector_type(8)));
typedef _Float16 f16x2 __attribute__((ext_vector_type(2)));
typedef float f32x4 __attribute__((ext_vector_type(4)));
typedef unsigned short us4 __attribute__((ext_vector_type(4)));
typedef unsigned short us8 __attribute__((ext_vector_type(8)));

__device__ __forceinline__ unsigned short f2h(float f) {
  union { _Float16 h; unsigned short u; } v;
  v.h = (_Float16)f;
  return v.u;
}
__device__ __forceinline__ f16x2 hpair(float f) {
  const _Float16 h = (_Float16)f;
  return (f16x2){h, h};
}

// ---------------- Kernel 1: combined prep (fp16), unchanged.
__global__ __launch_bounds__(256) void k_pre(const float* __restrict__ x,
                                             const float* __restrict__ w_df,
                                             const float* __restrict__ w_tm,
                                             const float* __restrict__ w_tr,
                                             unsigned short* __restrict__ xt,
                                             unsigned short* __restrict__ wfrag,
                                             unsigned short* __restrict__ w6p) {
  const int b = blockIdx.x;
  const int tid = threadIdx.x;
  if (b < 576) {
    __shared__ unsigned short tile[64][130];
    const int pt = b % 144;          // 144 p-tiles of 64
    const int ch = (b / 144) & 1;    // 2 c-halves of 128
    const int n  = b / 288;
    const int p0 = pt * 64, c0 = ch * 128;
    const float* xp = x + (size_t)n * C_ * HW_;
    unsigned short* xtp = xt + (size_t)n * C_ * HW_;
    const int tx = tid & 15, ty = tid >> 4;  // 16 p-chunks x 16 c-rows
#pragma unroll
    for (int pass = 0; pass < 8; pass++) {
      const int c = pass * 16 + ty;
      const f32x4 v = *(const f32x4*)(xp + (size_t)(c0 + c) * HW_ + p0 + tx * 4);
#pragma unroll
      for (int i = 0; i < 4; i++) tile[tx * 4 + i][c] = f2h(v[i]);
    }
    __syncthreads();
    const int l32 = tid & 31, pr = tid >> 5;  // 32 c-chunks x 8 p-rows
#pragma unroll
    for (int pass = 0; pass < 8; pass++) {
      const int p = pass * 8 + pr;
      us4 v;
#pragma unroll
      for (int i = 0; i < 4; i++) v[i] = tile[p][l32 * 4 + i];
      *(us4*)(xtp + (size_t)(p0 + p) * C_ + c0 + l32 * 4) = v;
    }
  } else if (b < 864) {
    const int base = (b - 576) * 2048 + tid * 8;  // < 589824
    const int l  = (base >> 3) & 63;
    const int g  = (base >> 9) & 15;
    const int ks = (base >> 13) & 7;
    const int t  = base >> 16;
    const int o  = g * 16 + (l & 15);
    const int c  = ks * 32 + (l >> 4) * 8;
    us8 res;
#pragma unroll
    for (int j = 0; j < 8; j++) res[j] = f2h(w_df[(size_t)(o * 256 + c + j) * 9 + t]);
    *(us8*)(wfrag + base) = res;
  } else {
    int idx = (b - 864) * 256 + tid;   // < 9*16*256 = 36864
    int t = idx >> 12;
    int r = idx & 4095;
    int j = r >> 8;
    int c = r & 255;
    float v = 0.f;
    if (j < 4) v = w_tm[(size_t)(j * C_ + c) * 9 + t];
    else if (j < 6) v = w_tr[(size_t)((j - 4) * C_ + c) * 9 + t];
    w6p[idx] = f2h(v);
  }
}

// ---------------- Kernel 2: FUSED offsets + sample + GEMM + BN + res + ReLU.
// v14 = v13 with the ONE fix: __launch_bounds__(1024, 2).
// r11's failure was NOT structural: launch_bounds(1024) defaulted the
// min-waves arg to 4 -> VGPR cap 256/4 = 64 (session law, 6-for-6) ->
// ~60MB scratch spill (WRITE 18.7->80MB) -> 100us. The 16-wave m-split
// structure itself reached 35% occupancy as designed.
// (1024,2) -> cap 256/2 = 128; 4 waves/SIMD x 128 = exactly the 512-reg
// pool. State needs ~110 -> spill-free. Tripwire: WRITE_SIZE must return
// to ~18.4-18.7MB and VGPR_Count to ~110-128.
__global__ __launch_bounds__(1024, 2) void k_fused(const unsigned short* __restrict__ xt,
                                                   const unsigned short* __restrict__ Wfrag,
                                                   const unsigned short* __restrict__ w6p,
                                                   const float* __restrict__ b_tm,
                                                   const float* __restrict__ b_tr,
                                                   const float* __restrict__ xres,
                                                   const float* __restrict__ gamma,
                                                   const float* __restrict__ beta,
                                                   const float* __restrict__ mean,
                                                   const float* __restrict__ var,
                                                   float* __restrict__ out) {
  __shared__ unsigned short As[2][80 * 256] __attribute__((aligned(16)));  // 80KB
  __shared__ float sred5[5][8][16][8];     // 20.5KB (prologue only)
  __shared__ float coords_s[80][9][2];     // 5.76KB
  __shared__ int   nofs[80];               // per-row xt element offset (n*C*HW)
  const int tid = threadIdx.x;
  const int wave = tid >> 6, lane = tid & 63;
  const int w7 = wave & 7, half = wave >> 3;
  const int row = lane & 15, quad = lane >> 4;
  // XCD-clustered bijective map: 256 blocks -> pb 0..255, 32 per XCD.
  const int pb = (blockIdx.x & 7) * 32 + (blockIdx.x >> 3);
  const bool fat = pb < 128;
  const int nt = fat ? 5 : 4;              // 16-row tiles in this block
  const int m0 = fat ? pb * 80 : 10240 + (pb - 128) * 64;
  // GEMM m-split: this wave's tile base and count
  const int tb  = half ? (fat ? 3 : 2) : 0;
  const int ntw = half ? 2 : (fat ? 3 : 2);
  const int sr = tid >> 4;  // staging row 0..63 (one row per thread)
  const int cg = tid & 15;  // staging 16-channel group

  // ---- Prologue: offset conv, per 16-row tile; tile parity by wave-half ----
#pragma unroll
  for (int t5 = 0; t5 < 5; ++t5) {
    if (t5 < nt && (t5 & 1) == half) {
      const int ts = m0 + t5 * 16;
      const int nn = ts / HW_;
      const int hw = ts - nn * HW_;
      const int h = hw / W_, w0 = hw - h * W_;  // w0 multiple of 16
      const unsigned short* xts = xt + (size_t)nn * C_ * HW_;
      const int cq = w7 * 32;   // 8 waves/group x 32ch = full K per tap
      f32x4 oacc = {0.f, 0.f, 0.f, 0.f};
      const f16x8 zero8 = {};
#pragma unroll
      for (int t = 0; t < 9; t++) {
        const int ty = t / 3, tx = t % 3;
        const int y = h + ty - 1;
        if (y < 0 || y >= H_) continue;  // tile-uniform
        const int xx = w0 + row + tx - 1;
        const bool valid = (xx >= 0) && (xx < W_);
        const int xc = min(max(xx, 0), W_ - 1);
        f16x8 av = *(const f16x8*)(const void*)(xts + (size_t)(y * W_ + xc) * C_ + cq + quad * 8);
        if (!valid) av = zero8;
        const f16x8 bv = *(const f16x8*)(const void*)(w6p + (size_t)(t * 16 + row) * C_ + cq + quad * 8);
        oacc = __builtin_amdgcn_mfma_f32_16x16x32_f16(av, bv, oacc, 0, 0, 0);
      }
      if (row < 6) {
#pragma unroll
        for (int r = 0; r < 4; r++) sred5[t5][w7][quad * 4 + r][row] = oacc[r];
      }
    }
  }
  __syncthreads();
  if (tid < nt * 16) {
    const int rg = tid;                 // row in block
    const int gm = m0 + rg;
    const int nn = gm / HW_;
    const int hw = gm - nn * HW_;
    const int h = hw / W_, w = hw - h * W_;
    const int tt = rg >> 4, mm = rg & 15;
    float a[6];
#pragma unroll
    for (int j = 0; j < 6; j++) {
      float s = 0.f;
#pragma unroll
      for (int wv = 0; wv < 8; wv++) s += sred5[tt][wv][mm][j];
      a[j] = s;
    }
    const float tm0 = a[0] + b_tm[0];
    const float tm1 = a[1] + b_tm[1];
    const float tm2 = a[2] + b_tm[2];
    const float tm3 = a[3] + b_tm[3];
    const float tr0 = a[4] + b_tr[0];
    const float tr1 = a[5] + b_tr[1];
#pragma unroll
    for (int t = 0; t < 9; t++) {
      const float ry = (float)(t / 3) - 1.f;
      const float rx = (float)(t % 3) - 1.f;
      coords_s[rg][t][0] = (float)h + tr0 + tm0 * ry + tm1 * rx;
      coords_s[rg][t][1] = (float)w + tr1 + tm2 * ry + tm3 * rx;
    }
    nofs[rg] = nn * (C_ * HW_);
  }
  __syncthreads();

  // ---- Main loop over 9 taps, pipelined staging ----
  f32x4 acc[3][2] = {};   // [m-tile within wave][o-frag]
  float cwA[4];
  us8 uA0[4], uA1[4];     // one corner register set

  // compute weights + issue 8 corner loads for row R of tap TAP
#define ISSUE(R, TAP)                                                          \
  {                                                                            \
    const int r_ = (R);                                                        \
    const int nof = nofs[r_];                                                  \
    const float py = coords_s[r_][TAP][0];                                     \
    const float px = coords_s[r_][TAP][1];                                     \
    const float fy = floorf(py), fx = floorf(px);                              \
    const float wy = py - fy, wx = px - fx;                                    \
    const int y0 = (int)fy, x0 = (int)fx;                                      \
    const int y1 = y0 + 1, x1 = x0 + 1;                                        \
    const float vy0 = (y0 >= 0 && y0 < H_) ? 1.f : 0.f;                        \
    const float vy1 = (y1 >= 0 && y1 < H_) ? 1.f : 0.f;                        \
    const float vx0 = (x0 >= 0 && x0 < W_) ? 1.f : 0.f;                        \
    const float vx1 = (x1 >= 0 && x1 < W_) ? 1.f : 0.f;                        \
    cwA[0] = (1.f - wy) * (1.f - wx) * vy0 * vx0;                              \
    cwA[1] = (1.f - wy) * wx * vy0 * vx1;                                      \
    cwA[2] = wy * (1.f - wx) * vy1 * vx0;                                      \
    cwA[3] = wy * wx * vy1 * vx1;                                              \
    const int cy0 = min(max(y0, 0), H_ - 1), cy1 = min(max(y1, 0), H_ - 1);    \
    const int cx0 = min(max(x0, 0), W_ - 1), cx1 = min(max(x1, 0), W_ - 1);    \
    const int b0 = nof + (cy0 * W_ + cx0) * C_ + cg * 16;                      \
    const int b1 = nof + (cy0 * W_ + cx1) * C_ + cg * 16;                      \
    const int b2 = nof + (cy1 * W_ + cx0) * C_ + cg * 16;                      \
    const int b3 = nof + (cy1 * W_ + cx1) * C_ + cg * 16;                      \
    uA0[0] = *(const us8*)(xt + b0); uA1[0] = *(const us8*)(xt + b0 + 8);      \
    uA0[1] = *(const us8*)(xt + b1); uA1[1] = *(const us8*)(xt + b1 + 8);      \
    uA0[2] = *(const us8*)(xt + b2); uA1[2] = *(const us8*)(xt + b2 + 8);      \
    uA0[3] = *(const us8*)(xt + b3); uA1[3] = *(const us8*)(xt + b3 + 8);      \
  }

  // lerp the set and write row R into ASB (swizzled slot=(q&24)|((q^R)&7))
#define LERPW(R, ASB)                                                          \
  {                                                                            \
    const int r_ = (R);                                                        \
    const f16x2 c0 = hpair(cwA[0]), c1 = hpair(cwA[1]);                        \
    const f16x2 c2 = hpair(cwA[2]), c3 = hpair(cwA[3]);                        \
    us8 r0v, r1v;                                                              \
    {                                                                          \
      const f16x2* p0 = (const f16x2*)&uA0[0];                                 \
      const f16x2* p1 = (const f16x2*)&uA0[1];                                 \
      const f16x2* p2 = (const f16x2*)&uA0[2];                                 \
      const f16x2* p3 = (const f16x2*)&uA0[3];                                 \
      f16x2* d = (f16x2*)&r0v;                                                 \
      _Pragma("unroll")                                                        \
      for (int p = 0; p < 4; p++) {                                            \
        f16x2 r = p0[p] * c0; r = p1[p] * c1 + r;                              \
        r = p2[p] * c2 + r;   r = p3[p] * c3 + r;  d[p] = r;                   \
      }                                                                        \
    }                                                                          \
    {                                                                          \
      const f16x2* p0 = (const f16x2*)&uA1[0];                                 \
      const f16x2* p1 = (const f16x2*)&uA1[1];                                 \
      const f16x2* p2 = (const f16x2*)&uA1[2];                                 \
      const f16x2* p3 = (const f16x2*)&uA1[3];                                 \
      f16x2* d = (f16x2*)&r1v;                                                 \
      _Pragma("unroll")                                                        \
      for (int p = 0; p < 4; p++) {                                            \
        f16x2 r = p0[p] * c0; r = p1[p] * c1 + r;                              \
        r = p2[p] * c2 + r;   r = p3[p] * c3 + r;  d[p] = r;                   \
      }                                                                        \
    }                                                                          \
    const int q0i = cg * 2, q1i = cg * 2 + 1;                                  \
    const int s0 = (q0i & 24) | ((q0i ^ r_) & 7);                              \
    const int s1 = (q1i & 24) | ((q1i ^ r_) & 7);                              \
    *(us8*)(void*)&ASB[r_ * 256 + s0 * 8] = r0v;                               \
    *(us8*)(void*)&ASB[r_ * 256 + s1 * 8] = r1v;                               \
  }

  // One GEMM step: MFMAs with pair (BX,BY); load pair for KS+2 into them.
#define GS(KS, BX, BY)                                                         \
  {                                                                            \
    const int q = (KS) * 4 + quad;                                             \
    const int slot = (q & 24) | ((q ^ row) & 7);                               \
    f16x8 a0 = *(const f16x8*)(const void*)&asb[((tb + 0) * 16 + row) * 256 + slot * 8]; \
    f16x8 a1 = *(const f16x8*)(const void*)&asb[((tb + 1) * 16 + row) * 256 + slot * 8]; \
    f16x8 a2;                                                                  \
    if (ntw > 2) a2 = *(const f16x8*)(const void*)&asb[((tb + 2) * 16 + row) * 256 + slot * 8]; \
    f16x8 nx, ny;                                                              \
    if ((KS) < 6) {                                                            \
      const unsigned short* wfn = wfTap + (size_t)((KS) + 2) * 8192;           \
      nx = *(const f16x8*)(const void*)(wfn);                                  \
      ny = *(const f16x8*)(const void*)(wfn + 512);                            \
    }                                                                          \
    acc[0][0] = __builtin_amdgcn_mfma_f32_16x16x32_f16(a0, BX, acc[0][0], 0, 0, 0); \
    acc[0][1] = __builtin_amdgcn_mfma_f32_16x16x32_f16(a0, BY, acc[0][1], 0, 0, 0); \
    acc[1][0] = __builtin_amdgcn_mfma_f32_16x16x32_f16(a1, BX, acc[1][0], 0, 0, 0); \
    acc[1][1] = __builtin_amdgcn_mfma_f32_16x16x32_f16(a1, BY, acc[1][1], 0, 0, 0); \
    if (ntw > 2) {                                                             \
      acc[2][0] = __builtin_amdgcn_mfma_f32_16x16x32_f16(a2, BX, acc[2][0], 0, 0, 0); \
      acc[2][1] = __builtin_amdgcn_mfma_f32_16x16x32_f16(a2, BY, acc[2][1], 0, 0, 0); \
    }                                                                          \
    if ((KS) < 6) { BX = nx; BY = ny; }                                        \
  }

  const bool third = fat && (sr < 16);  // wave-uniform (waves 0-3)

  // prime the pipeline: corners for (sr, tap 0)
  ISSUE(sr, 0);
  __builtin_amdgcn_sched_barrier(0);

  for (int tap = 0; tap < 9; tap++) {
    unsigned short* __restrict__ asb = &As[tap & 1][0];
    const unsigned short* wfTap =
        Wfrag + (size_t)tap * 65536 + w7 * 1024 + lane * 8;

    // B pairs for ks0,ks1 issued pre-lerp: latency hides under lerp VALU,
    // completed by the barrier's vmcnt drain.
    f16x8 B0 = *(const f16x8*)(const void*)(wfTap);
    f16x8 B1 = *(const f16x8*)(const void*)(wfTap + 512);
    f16x8 B2 = *(const f16x8*)(const void*)(wfTap + 8192);
    f16x8 B3 = *(const f16x8*)(const void*)(wfTap + 8704);
    __builtin_amdgcn_sched_barrier(0);

    LERPW(sr, asb);
    if (third) {            // fat extra rows 64..79: short serial chain
      ISSUE(sr + 64, tap);
      __builtin_amdgcn_sched_barrier(0);
      LERPW(sr + 64, asb);
    }

    __syncthreads();  // ONE barrier per tap (drains all pre-barrier loads)

    if (tap < 8) {    // cross-tap prefetch: hidden under the whole ks loop
      ISSUE(sr, tap + 1);
      __builtin_amdgcn_sched_barrier(0);
    }

    GS(0, B0, B1)
    GS(1, B2, B3)
    GS(2, B0, B1)
    GS(3, B2, B3)
    GS(4, B0, B1)
    GS(5, B2, B3)
    GS(6, B0, B1)
    GS(7, B2, B3)
    // NO trailing barrier: As double-buffered; next write to As[tap&1]
    // happens after barrier(tap+1), which orders all reads of As[tap&1].
  }

  // ---- Epilogue: BN + residual + ReLU, this wave's tiles x 32-o range ----
#pragma unroll
  for (int ot = 0; ot < 2; ot++) {
    const int o = w7 * 32 + ot * 16 + row;
    const float sc = rsqrtf(var[o] + 1e-5f) * gamma[o];
    const float bi = beta[o] - mean[o] * sc;
#pragma unroll
    for (int i = 0; i < 3; i++) {
      if (i < ntw) {
        const int t5 = tb + i;
        const int ts = m0 + t5 * 16;
        const int nn = ts / HW_;
        const int hw0 = ts - nn * HW_ + quad * 4;
        const size_t ob = (size_t)(nn * O_ + o) * HW_ + hw0;
        const f32x4 rv = *(const f32x4*)(xres + ob);
        f32x4 ov;
#pragma unroll
        for (int r = 0; r < 4; r++) ov[r] = fmaxf(acc[i][ot][r] * sc + bi + rv[r], 0.f);
        *(f32x4*)(out + ob) = ov;
      }
    }
  }
}

extern "C" void kernel_launch(void* const* d_in, const int* in_sizes, int n_in,
                              void* d_out, int out_size, void* d_ws, size_t ws_size,
                              hipStream_t stream) {
  const float* x     = (const float*)d_in[0];
  const float* w_tm  = (const float*)d_in[2];
  const float* b_tm  = (const float*)d_in[3];
  const float* w_tr  = (const float*)d_in[4];
  const float* b_tr  = (const float*)d_in[5];
  const float* w_df  = (const float*)d_in[6];
  const float* gamma = (const float*)d_in[7];
  const float* beta  = (const float*)d_in[8];
  const float* mean  = (const float*)d_in[9];
  const float* var   = (const float*)d_in[10];
  float* out = (float*)d_out;

  char* ws = (char*)d_ws;
  unsigned short* xt    = (unsigned short*)(ws);                       //  9,437,184 B
  unsigned short* wfrag = (unsigned short*)(ws + 9437184);             //  1,179,648 B
  unsigned short* w6p   = (unsigned short*)(ws + 9437184 + 1179648);   //     73,728 B

  k_pre<<<1008, 256, 0, stream>>>(x, w_df, w_tm, w_tr, xt, wfrag, w6p);
  k_fused<<<256, 1024, 0, stream>>>(xt, wfrag, w6p, b_tm, b_tr, x,
                                    gamma, beta, mean, var, out);
}

// Round 13
// 192.651 us; speedup vs baseline: 1.0085x; 1.0054x over previous
//
#include <hip/hip_runtime.h>
#include <stdint.h>

#define H_ 96
#define W_ 96
#define C_ 256
#define O_ 256
#define N_ 2
#define HW_ (H_*W_)          // 9216
#define M_ (N_*HW_)          // 18432
#define GK 2304              // C_*9

typedef _Float16 f16x8 __attribute__((ext_vector_type(8)));
typedef _Float16 f16x2 __attribute__((ext_vector_type(2)));
typedef float f32x4 __attribute__((ext_vector_type(4)));
typedef unsigned short us4 __attribute__((ext_vector_type(4)));
typedef unsigned short us8 __attribute__((ext_vector_type(8)));

__device__ __forceinline__ unsigned short f2h(float f) {
  union { _Float16 h; unsigned short u; } v;
  v.h = (_Float16)f;
  return v.u;
}
__device__ __forceinline__ f16x2 hpair(float f) {
  const _Float16 h = (_Float16)f;
  return (f16x2){h, h};
}

// ---------------- Kernel 1: combined prep (fp16), unchanged.
__global__ __launch_bounds__(256) void k_pre(const float* __restrict__ x,
                                             const float* __restrict__ w_df,
                                             const float* __restrict__ w_tm,
                                             const float* __restrict__ w_tr,
                                             unsigned short* __restrict__ xt,
                                             unsigned short* __restrict__ wfrag,
                                             unsigned short* __restrict__ w6p) {
  const int b = blockIdx.x;
  const int tid = threadIdx.x;
  if (b < 576) {
    __shared__ unsigned short tile[64][130];
    const int pt = b % 144;          // 144 p-tiles of 64
    const int ch = (b / 144) & 1;    // 2 c-halves of 128
    const int n  = b / 288;
    const int p0 = pt * 64, c0 = ch * 128;
    const float* xp = x + (size_t)n * C_ * HW_;
    unsigned short* xtp = xt + (size_t)n * C_ * HW_;
    const int tx = tid & 15, ty = tid >> 4;  // 16 p-chunks x 16 c-rows
#pragma unroll
    for (int pass = 0; pass < 8; pass++) {
      const int c = pass * 16 + ty;
      const f32x4 v = *(const f32x4*)(xp + (size_t)(c0 + c) * HW_ + p0 + tx * 4);
#pragma unroll
      for (int i = 0; i < 4; i++) tile[tx * 4 + i][c] = f2h(v[i]);
    }
    __syncthreads();
    const int l32 = tid & 31, pr = tid >> 5;  // 32 c-chunks x 8 p-rows
#pragma unroll
    for (int pass = 0; pass < 8; pass++) {
      const int p = pass * 8 + pr;
      us4 v;
#pragma unroll
      for (int i = 0; i < 4; i++) v[i] = tile[p][l32 * 4 + i];
      *(us4*)(xtp + (size_t)(p0 + p) * C_ + c0 + l32 * 4) = v;
    }
  } else if (b < 864) {
    const int base = (b - 576) * 2048 + tid * 8;  // < 589824
    const int l  = (base >> 3) & 63;
    const int g  = (base >> 9) & 15;
    const int ks = (base >> 13) & 7;
    const int t  = base >> 16;
    const int o  = g * 16 + (l & 15);
    const int c  = ks * 32 + (l >> 4) * 8;
    us8 res;
#pragma unroll
    for (int j = 0; j < 8; j++) res[j] = f2h(w_df[(size_t)(o * 256 + c + j) * 9 + t]);
    *(us8*)(wfrag + base) = res;
  } else {
    int idx = (b - 864) * 256 + tid;   // < 9*16*256 = 36864
    int t = idx >> 12;
    int r = idx & 4095;
    int j = r >> 8;
    int c = r & 255;
    float v = 0.f;
    if (j < 4) v = w_tm[(size_t)(j * C_ + c) * 9 + t];
    else if (j < 6) v = w_tr[(size_t)((j - 4) * C_ + c) * 9 + t];
    w6p[idx] = f2h(v);
  }
}

// ---------------- Kernel 2: FUSED offsets + sample + GEMM + BN + res + ReLU.
// v15 = v13/v14 with __launch_bounds__(1024, 1).
// SESSION LAW (7/7 fit): the 2nd launch_bounds arg acts as MIN BLOCKS PER
// CU (CUDA semantics); VGPR cap = 512 / (blocks x waves_per_block_per_SIMD).
//   (512,4)->64, (512,8)->32, (512,3)->85, (512,2)->128,
//   (1024,def)->64, (1024,2)->64 [2 blk x 4 w/SIMD = 8 -> 512/8],
//   (1024,1)->  1 blk x 4 w/SIMD = 4 -> 512/4 = 128.  <- this kernel
// r11/r12 both PASSED (structure correct) but spilled ~60MB at cap 64.
// With cap 128 the ~110-VGPR state fits. Tripwires: VGPR_Count ~110-128,
// WRITE_SIZE back to ~18.4-18.7MB, hbm_bytes ~4e7.
__global__ __launch_bounds__(1024, 1) void k_fused(const unsigned short* __restrict__ xt,
                                                   const unsigned short* __restrict__ Wfrag,
                                                   const unsigned short* __restrict__ w6p,
                                                   const float* __restrict__ b_tm,
                                                   const float* __restrict__ b_tr,
                                                   const float* __restrict__ xres,
                                                   const float* __restrict__ gamma,
                                                   const float* __restrict__ beta,
                                                   const float* __restrict__ mean,
                                                   const float* __restrict__ var,
                                                   float* __restrict__ out) {
  __shared__ unsigned short As[2][80 * 256] __attribute__((aligned(16)));  // 80KB
  __shared__ float sred5[5][8][16][8];     // 20.5KB (prologue only)
  __shared__ float coords_s[80][9][2];     // 5.76KB
  __shared__ int   nofs[80];               // per-row xt element offset (n*C*HW)
  const int tid = threadIdx.x;
  const int wave = tid >> 6, lane = tid & 63;
  const int w7 = wave & 7, half = wave >> 3;
  const int row = lane & 15, quad = lane >> 4;
  // XCD-clustered bijective map: 256 blocks -> pb 0..255, 32 per XCD.
  const int pb = (blockIdx.x & 7) * 32 + (blockIdx.x >> 3);
  const bool fat = pb < 128;
  const int nt = fat ? 5 : 4;              // 16-row tiles in this block
  const int m0 = fat ? pb * 80 : 10240 + (pb - 128) * 64;
  // GEMM m-split: this wave's tile base and count
  const int tb  = half ? (fat ? 3 : 2) : 0;
  const int ntw = half ? 2 : (fat ? 3 : 2);
  const int sr = tid >> 4;  // staging row 0..63 (one row per thread)
  const int cg = tid & 15;  // staging 16-channel group

  // ---- Prologue: offset conv, per 16-row tile; tile parity by wave-half ----
#pragma unroll
  for (int t5 = 0; t5 < 5; ++t5) {
    if (t5 < nt && (t5 & 1) == half) {
      const int ts = m0 + t5 * 16;
      const int nn = ts / HW_;
      const int hw = ts - nn * HW_;
      const int h = hw / W_, w0 = hw - h * W_;  // w0 multiple of 16
      const unsigned short* xts = xt + (size_t)nn * C_ * HW_;
      const int cq = w7 * 32;   // 8 waves/group x 32ch = full K per tap
      f32x4 oacc = {0.f, 0.f, 0.f, 0.f};
      const f16x8 zero8 = {};
#pragma unroll
      for (int t = 0; t < 9; t++) {
        const int ty = t / 3, tx = t % 3;
        const int y = h + ty - 1;
        if (y < 0 || y >= H_) continue;  // tile-uniform
        const int xx = w0 + row + tx - 1;
        const bool valid = (xx >= 0) && (xx < W_);
        const int xc = min(max(xx, 0), W_ - 1);
        f16x8 av = *(const f16x8*)(const void*)(xts + (size_t)(y * W_ + xc) * C_ + cq + quad * 8);
        if (!valid) av = zero8;
        const f16x8 bv = *(const f16x8*)(const void*)(w6p + (size_t)(t * 16 + row) * C_ + cq + quad * 8);
        oacc = __builtin_amdgcn_mfma_f32_16x16x32_f16(av, bv, oacc, 0, 0, 0);
      }
      if (row < 6) {
#pragma unroll
        for (int r = 0; r < 4; r++) sred5[t5][w7][quad * 4 + r][row] = oacc[r];
      }
    }
  }
  __syncthreads();
  if (tid < nt * 16) {
    const int rg = tid;                 // row in block
    const int gm = m0 + rg;
    const int nn = gm / HW_;
    const int hw = gm - nn * HW_;
    const int h = hw / W_, w = hw - h * W_;
    const int tt = rg >> 4, mm = rg & 15;
    float a[6];
#pragma unroll
    for (int j = 0; j < 6; j++) {
      float s = 0.f;
#pragma unroll
      for (int wv = 0; wv < 8; wv++) s += sred5[tt][wv][mm][j];
      a[j] = s;
    }
    const float tm0 = a[0] + b_tm[0];
    const float tm1 = a[1] + b_tm[1];
    const float tm2 = a[2] + b_tm[2];
    const float tm3 = a[3] + b_tm[3];
    const float tr0 = a[4] + b_tr[0];
    const float tr1 = a[5] + b_tr[1];
#pragma unroll
    for (int t = 0; t < 9; t++) {
      const float ry = (float)(t / 3) - 1.f;
      const float rx = (float)(t % 3) - 1.f;
      coords_s[rg][t][0] = (float)h + tr0 + tm0 * ry + tm1 * rx;
      coords_s[rg][t][1] = (float)w + tr1 + tm2 * ry + tm3 * rx;
    }
    nofs[rg] = nn * (C_ * HW_);
  }
  __syncthreads();

  // ---- Main loop over 9 taps, pipelined staging ----
  f32x4 acc[3][2] = {};   // [m-tile within wave][o-frag]
  float cwA[4];
  us8 uA0[4], uA1[4];     // one corner register set

  // compute weights + issue 8 corner loads for row R of tap TAP
#define ISSUE(R, TAP)                                                          \
  {                                                                            \
    const int r_ = (R);                                                        \
    const int nof = nofs[r_];                                                  \
    const float py = coords_s[r_][TAP][0];                                     \
    const float px = coords_s[r_][TAP][1];                                     \
    const float fy = floorf(py), fx = floorf(px);                              \
    const float wy = py - fy, wx = px - fx;                                    \
    const int y0 = (int)fy, x0 = (int)fx;                                      \
    const int y1 = y0 + 1, x1 = x0 + 1;                                        \
    const float vy0 = (y0 >= 0 && y0 < H_) ? 1.f : 0.f;                        \
    const float vy1 = (y1 >= 0 && y1 < H_) ? 1.f : 0.f;                        \
    const float vx0 = (x0 >= 0 && x0 < W_) ? 1.f : 0.f;                        \
    const float vx1 = (x1 >= 0 && x1 < W_) ? 1.f : 0.f;                        \
    cwA[0] = (1.f - wy) * (1.f - wx) * vy0 * vx0;                              \
    cwA[1] = (1.f - wy) * wx * vy0 * vx1;                                      \
    cwA[2] = wy * (1.f - wx) * vy1 * vx0;                                      \
    cwA[3] = wy * wx * vy1 * vx1;                                              \
    const int cy0 = min(max(y0, 0), H_ - 1), cy1 = min(max(y1, 0), H_ - 1);    \
    const int cx0 = min(max(x0, 0), W_ - 1), cx1 = min(max(x1, 0), W_ - 1);    \
    const int b0 = nof + (cy0 * W_ + cx0) * C_ + cg * 16;                      \
    const int b1 = nof + (cy0 * W_ + cx1) * C_ + cg * 16;                      \
    const int b2 = nof + (cy1 * W_ + cx0) * C_ + cg * 16;                      \
    const int b3 = nof + (cy1 * W_ + cx1) * C_ + cg * 16;                      \
    uA0[0] = *(const us8*)(xt + b0); uA1[0] = *(const us8*)(xt + b0 + 8);      \
    uA0[1] = *(const us8*)(xt + b1); uA1[1] = *(const us8*)(xt + b1 + 8);      \
    uA0[2] = *(const us8*)(xt + b2); uA1[2] = *(const us8*)(xt + b2 + 8);      \
    uA0[3] = *(const us8*)(xt + b3); uA1[3] = *(const us8*)(xt + b3 + 8);      \
  }

  // lerp the set and write row R into ASB (swizzled slot=(q&24)|((q^R)&7))
#define LERPW(R, ASB)                                                          \
  {                                                                            \
    const int r_ = (R);                                                        \
    const f16x2 c0 = hpair(cwA[0]), c1 = hpair(cwA[1]);                        \
    const f16x2 c2 = hpair(cwA[2]), c3 = hpair(cwA[3]);                        \
    us8 r0v, r1v;                                                              \
    {                                                                          \
      const f16x2* p0 = (const f16x2*)&uA0[0];                                 \
      const f16x2* p1 = (const f16x2*)&uA0[1];                                 \
      const f16x2* p2 = (const f16x2*)&uA0[2];                                 \
      const f16x2* p3 = (const f16x2*)&uA0[3];                                 \
      f16x2* d = (f16x2*)&r0v;                                                 \
      _Pragma("unroll")                                                        \
      for (int p = 0; p < 4; p++) {                                            \
        f16x2 r = p0[p] * c0; r = p1[p] * c1 + r;                              \
        r = p2[p] * c2 + r;   r = p3[p] * c3 + r;  d[p] = r;                   \
      }                                                                        \
    }                                                                          \
    {                                                                          \
      const f16x2* p0 = (const f16x2*)&uA1[0];                                 \
      const f16x2* p1 = (const f16x2*)&uA1[1];                                 \
      const f16x2* p2 = (const f16x2*)&uA1[2];                                 \
      const f16x2* p3 = (const f16x2*)&uA1[3];                                 \
      f16x2* d = (f16x2*)&r1v;                                                 \
      _Pragma("unroll")                                                        \
      for (int p = 0; p < 4; p++) {                                            \
        f16x2 r = p0[p] * c0; r = p1[p] * c1 + r;                              \
        r = p2[p] * c2 + r;   r = p3[p] * c3 + r;  d[p] = r;                   \
      }                                                                        \
    }                                                                          \
    const int q0i = cg * 2, q1i = cg * 2 + 1;                                  \
    const int s0 = (q0i & 24) | ((q0i ^ r_) & 7);                              \
    const int s1 = (q1i & 24) | ((q1i ^ r_) & 7);                              \
    *(us8*)(void*)&ASB[r_ * 256 + s0 * 8] = r0v;                               \
    *(us8*)(void*)&ASB[r_ * 256 + s1 * 8] = r1v;                               \
  }

  // One GEMM step: MFMAs with pair (BX,BY); load pair for KS+2 into them.
#define GS(KS, BX, BY)                                                         \
  {                                                                            \
    const int q = (KS) * 4 + quad;                                             \
    const int slot = (q & 24) | ((q ^ row) & 7);                               \
    f16x8 a0 = *(const f16x8*)(const void*)&asb[((tb + 0) * 16 + row) * 256 + slot * 8]; \
    f16x8 a1 = *(const f16x8*)(const void*)&asb[((tb + 1) * 16 + row) * 256 + slot * 8]; \
    f16x8 a2;                                                                  \
    if (ntw > 2) a2 = *(const f16x8*)(const void*)&asb[((tb + 2) * 16 + row) * 256 + slot * 8]; \
    f16x8 nx, ny;                                                              \
    if ((KS) < 6) {                                                            \
      const unsigned short* wfn = wfTap + (size_t)((KS) + 2) * 8192;           \
      nx = *(const f16x8*)(const void*)(wfn);                                  \
      ny = *(const f16x8*)(const void*)(wfn + 512);                            \
    }                                                                          \
    acc[0][0] = __builtin_amdgcn_mfma_f32_16x16x32_f16(a0, BX, acc[0][0], 0, 0, 0); \
    acc[0][1] = __builtin_amdgcn_mfma_f32_16x16x32_f16(a0, BY, acc[0][1], 0, 0, 0); \
    acc[1][0] = __builtin_amdgcn_mfma_f32_16x16x32_f16(a1, BX, acc[1][0], 0, 0, 0); \
    acc[1][1] = __builtin_amdgcn_mfma_f32_16x16x32_f16(a1, BY, acc[1][1], 0, 0, 0); \
    if (ntw > 2) {                                                             \
      acc[2][0] = __builtin_amdgcn_mfma_f32_16x16x32_f16(a2, BX, acc[2][0], 0, 0, 0); \
      acc[2][1] = __builtin_amdgcn_mfma_f32_16x16x32_f16(a2, BY, acc[2][1], 0, 0, 0); \
    }                                                                          \
    if ((KS) < 6) { BX = nx; BY = ny; }                                        \
  }

  const bool third = fat && (sr < 16);  // wave-uniform (waves 0-3)

  // prime the pipeline: corners for (sr, tap 0)
  ISSUE(sr, 0);
  __builtin_amdgcn_sched_barrier(0);

  for (int tap = 0; tap < 9; tap++) {
    unsigned short* __restrict__ asb = &As[tap & 1][0];
    const unsigned short* wfTap =
        Wfrag + (size_t)tap * 65536 + w7 * 1024 + lane * 8;

    // B pairs for ks0,ks1 issued pre-lerp: latency hides under lerp VALU,
    // completed by the barrier's vmcnt drain.
    f16x8 B0 = *(const f16x8*)(const void*)(wfTap);
    f16x8 B1 = *(const f16x8*)(const void*)(wfTap + 512);
    f16x8 B2 = *(const f16x8*)(const void*)(wfTap + 8192);
    f16x8 B3 = *(const f16x8*)(const void*)(wfTap + 8704);
    __builtin_amdgcn_sched_barrier(0);

    LERPW(sr, asb);
    if (third) {            // fat extra rows 64..79: short serial chain
      ISSUE(sr + 64, tap);
      __builtin_amdgcn_sched_barrier(0);
      LERPW(sr + 64, asb);
    }

    __syncthreads();  // ONE barrier per tap (drains all pre-barrier loads)

    if (tap < 8) {    // cross-tap prefetch: hidden under the whole ks loop
      ISSUE(sr, tap + 1);
      __builtin_amdgcn_sched_barrier(0);
    }

    GS(0, B0, B1)
    GS(1, B2, B3)
    GS(2, B0, B1)
    GS(3, B2, B3)
    GS(4, B0, B1)
    GS(5, B2, B3)
    GS(6, B0, B1)
    GS(7, B2, B3)
    // NO trailing barrier: As double-buffered; next write to As[tap&1]
    // happens after barrier(tap+1), which orders all reads of As[tap&1].
  }

  // ---- Epilogue: BN + residual + ReLU, this wave's tiles x 32-o range ----
#pragma unroll
  for (int ot = 0; ot < 2; ot++) {
    const int o = w7 * 32 + ot * 16 + row;
    const float sc = rsqrtf(var[o] + 1e-5f) * gamma[o];
    const float bi = beta[o] - mean[o] * sc;
#pragma unroll
    for (int i = 0; i < 3; i++) {
      if (i < ntw) {
        const int t5 = tb + i;
        const int ts = m0 + t5 * 16;
        const int nn = ts / HW_;
        const int hw0 = ts - nn * HW_ + quad * 4;
        const size_t ob = (size_t)(nn * O_ + o) * HW_ + hw0;
        const f32x4 rv = *(const f32x4*)(xres + ob);
        f32x4 ov;
#pragma unroll
        for (int r = 0; r < 4; r++) ov[r] = fmaxf(acc[i][ot][r] * sc + bi + rv[r], 0.f);
        *(f32x4*)(out + ob) = ov;
      }
    }
  }
}

extern "C" void kernel_launch(void* const* d_in, const int* in_sizes, int n_in,
                              void* d_out, int out_size, void* d_ws, size_t ws_size,
                              hipStream_t stream) {
  const float* x     = (const float*)d_in[0];
  const float* w_tm  = (const float*)d_in[2];
  const float* b_tm  = (const float*)d_in[3];
  const float* w_tr  = (const float*)d_in[4];
  const float* b_tr  = (const float*)d_in[5];
  const float* w_df  = (const float*)d_in[6];
  const float* gamma = (const float*)d_in[7];
  const float* beta  = (const float*)d_in[8];
  const float* mean  = (const float*)d_in[9];
  const float* var   = (const float*)d_in[10];
  float* out = (float*)d_out;

  char* ws = (char*)d_ws;
  unsigned short* xt    = (unsigned short*)(ws);                       //  9,437,184 B
  unsigned short* wfrag = (unsigned short*)(ws + 9437184);             //  1,179,648 B
  unsigned short* w6p   = (unsigned short*)(ws + 9437184 + 1179648);   //     73,728 B

  k_pre<<<1008, 256, 0, stream>>>(x, w_df, w_tm, w_tr, xt, wfrag, w6p);
  k_fused<<<256, 1024, 0, stream>>>(xt, wfrag, w6p, b_tm, b_tr, x,
                                    gamma, beta, mean, var, out);
}

// Round 14
// 156.397 us; speedup vs baseline: 1.2423x; 1.2318x over previous
//
#include <hip/hip_runtime.h>
#include <stdint.h>

#define H_ 96
#define W_ 96
#define C_ 256
#define O_ 256
#define N_ 2
#define HW_ (H_*W_)          // 9216
#define M_ (N_*HW_)          // 18432
#define GK 2304              // C_*9

typedef _Float16 f16x8 __attribute__((ext_vector_type(8)));
typedef _Float16 f16x2 __attribute__((ext_vector_type(2)));
typedef float f32x4 __attribute__((ext_vector_type(4)));
typedef unsigned short us4 __attribute__((ext_vector_type(4)));
typedef unsigned short us8 __attribute__((ext_vector_type(8)));

__device__ __forceinline__ unsigned short f2h(float f) {
  union { _Float16 h; unsigned short u; } v;
  v.h = (_Float16)f;
  return v.u;
}
__device__ __forceinline__ f16x2 hpair(float f) {
  const _Float16 h = (_Float16)f;
  return (f16x2){h, h};
}

// ---------------- Kernel 1: combined prep (fp16), unchanged.
__global__ __launch_bounds__(256) void k_pre(const float* __restrict__ x,
                                             const float* __restrict__ w_df,
                                             const float* __restrict__ w_tm,
                                             const float* __restrict__ w_tr,
                                             unsigned short* __restrict__ xt,
                                             unsigned short* __restrict__ wfrag,
                                             unsigned short* __restrict__ w6p) {
  const int b = blockIdx.x;
  const int tid = threadIdx.x;
  if (b < 576) {
    __shared__ unsigned short tile[64][130];
    const int pt = b % 144;          // 144 p-tiles of 64
    const int ch = (b / 144) & 1;    // 2 c-halves of 128
    const int n  = b / 288;
    const int p0 = pt * 64, c0 = ch * 128;
    const float* xp = x + (size_t)n * C_ * HW_;
    unsigned short* xtp = xt + (size_t)n * C_ * HW_;
    const int tx = tid & 15, ty = tid >> 4;  // 16 p-chunks x 16 c-rows
#pragma unroll
    for (int pass = 0; pass < 8; pass++) {
      const int c = pass * 16 + ty;
      const f32x4 v = *(const f32x4*)(xp + (size_t)(c0 + c) * HW_ + p0 + tx * 4);
#pragma unroll
      for (int i = 0; i < 4; i++) tile[tx * 4 + i][c] = f2h(v[i]);
    }
    __syncthreads();
    const int l32 = tid & 31, pr = tid >> 5;  // 32 c-chunks x 8 p-rows
#pragma unroll
    for (int pass = 0; pass < 8; pass++) {
      const int p = pass * 8 + pr;
      us4 v;
#pragma unroll
      for (int i = 0; i < 4; i++) v[i] = tile[p][l32 * 4 + i];
      *(us4*)(xtp + (size_t)(p0 + p) * C_ + c0 + l32 * 4) = v;
    }
  } else if (b < 864) {
    const int base = (b - 576) * 2048 + tid * 8;  // < 589824
    const int l  = (base >> 3) & 63;
    const int g  = (base >> 9) & 15;
    const int ks = (base >> 13) & 7;
    const int t  = base >> 16;
    const int o  = g * 16 + (l & 15);
    const int c  = ks * 32 + (l >> 4) * 8;
    us8 res;
#pragma unroll
    for (int j = 0; j < 8; j++) res[j] = f2h(w_df[(size_t)(o * 256 + c + j) * 9 + t]);
    *(us8*)(wfrag + base) = res;
  } else {
    int idx = (b - 864) * 256 + tid;   // < 9*16*256 = 36864
    int t = idx >> 12;
    int r = idx & 4095;
    int j = r >> 8;
    int c = r & 255;
    float v = 0.f;
    if (j < 4) v = w_tm[(size_t)(j * C_ + c) * 9 + t];
    else if (j < 6) v = w_tr[(size_t)((j - 4) * C_ + c) * 9 + t];
    w6p[idx] = f2h(v);
  }
}

// ---------------- Kernel 2: FUSED offsets + sample + GEMM + BN + res + ReLU.
// v16 = v12 (r10, best measured k_fused 68.0us: grid 256, 512 thr, 1
// block/CU, fat80/thin64, pipelined staging, VGPR 88 of 128 cap) with ONE
// change: ks-loop B prefetch deepened to depth-2 rotation (hold B0-B3; at
// step ks issue ks+2's pair -- the v7/v13 pattern). v12's depth-1 gave
// ~35 issue-cycles of slack vs ~200-300cy L2 latency; depth-2 doubles it.
// +16 persistent VGPR -> ~104, under the (512,2) cap of 128.
// SESSION LAW (final): 1024-thread blocks hard-cap at 64 VGPR regardless
// of launch_bounds (r11/r12/r13 all spilled 60MB); 512-thread + (512,2)
// reliably gives cap 128. Wide blocks abandoned.
// Tripwires: VGPR ~100-112, WRITE_SIZE 18.4-18.7MB, hbm_bytes ~4e7.
__global__ __launch_bounds__(512, 2) void k_fused(const unsigned short* __restrict__ xt,
                                                  const unsigned short* __restrict__ Wfrag,
                                                  const unsigned short* __restrict__ w6p,
                                                  const float* __restrict__ b_tm,
                                                  const float* __restrict__ b_tr,
                                                  const float* __restrict__ xres,
                                                  const float* __restrict__ gamma,
                                                  const float* __restrict__ beta,
                                                  const float* __restrict__ mean,
                                                  const float* __restrict__ var,
                                                  float* __restrict__ out) {
  __shared__ unsigned short As[2][80 * 256] __attribute__((aligned(16)));  // 80KB
  __shared__ float sred5[5][8][16][8];     // 20.5KB (prologue only)
  __shared__ float coords_s[80][9][2];     // 5.76KB
  __shared__ int   nofs[80];               // per-row xt element offset (n*C*HW)
  const int tid = threadIdx.x;
  const int wave = tid >> 6, lane = tid & 63;
  const int row = lane & 15, quad = lane >> 4;
  // XCD-clustered bijective map: 256 blocks -> pb 0..255, 32 per XCD.
  const int pb = (blockIdx.x & 7) * 32 + (blockIdx.x >> 3);
  const bool fat = pb < 128;
  const int nt = fat ? 5 : 4;              // 16-row tiles in this block
  const int m0 = fat ? pb * 80 : 10240 + (pb - 128) * 64;
  const int sr = tid >> 4;  // staging row 0..31
  const int cg = tid & 15;  // staging 16-channel group

  // ---- Prologue: offset conv, per 16-row tile (uniform n,h per tile) ----
#pragma unroll
  for (int t5 = 0; t5 < 5; ++t5) {
    if (t5 < nt) {
      const int ts = m0 + t5 * 16;
      const int nn = ts / HW_;
      const int hw = ts - nn * HW_;
      const int h = hw / W_, w0 = hw - h * W_;  // w0 multiple of 16
      const unsigned short* xts = xt + (size_t)nn * C_ * HW_;
      const int cq = wave * 32;   // 8 waves x 32ch = full K per tap
      f32x4 oacc = {0.f, 0.f, 0.f, 0.f};
      const f16x8 zero8 = {};
#pragma unroll
      for (int t = 0; t < 9; t++) {
        const int ty = t / 3, tx = t % 3;
        const int y = h + ty - 1;
        if (y < 0 || y >= H_) continue;  // tile-uniform
        const int xx = w0 + row + tx - 1;
        const bool valid = (xx >= 0) && (xx < W_);
        const int xc = min(max(xx, 0), W_ - 1);
        f16x8 av = *(const f16x8*)(const void*)(xts + (size_t)(y * W_ + xc) * C_ + cq + quad * 8);
        if (!valid) av = zero8;
        const f16x8 bv = *(const f16x8*)(const void*)(w6p + (size_t)(t * 16 + row) * C_ + cq + quad * 8);
        oacc = __builtin_amdgcn_mfma_f32_16x16x32_f16(av, bv, oacc, 0, 0, 0);
      }
      if (row < 6) {
#pragma unroll
        for (int r = 0; r < 4; r++) sred5[t5][wave][quad * 4 + r][row] = oacc[r];
      }
    }
  }
  __syncthreads();
  if (tid < nt * 16) {
    const int rg = tid;                 // row in block
    const int gm = m0 + rg;
    const int nn = gm / HW_;
    const int hw = gm - nn * HW_;
    const int h = hw / W_, w = hw - h * W_;
    const int tt = rg >> 4, mm = rg & 15;
    float a[6];
#pragma unroll
    for (int j = 0; j < 6; j++) {
      float s = 0.f;
#pragma unroll
      for (int wv = 0; wv < 8; wv++) s += sred5[tt][wv][mm][j];
      a[j] = s;
    }
    const float tm0 = a[0] + b_tm[0];
    const float tm1 = a[1] + b_tm[1];
    const float tm2 = a[2] + b_tm[2];
    const float tm3 = a[3] + b_tm[3];
    const float tr0 = a[4] + b_tr[0];
    const float tr1 = a[5] + b_tr[1];
#pragma unroll
    for (int t = 0; t < 9; t++) {
      const float ry = (float)(t / 3) - 1.f;
      const float rx = (float)(t % 3) - 1.f;
      coords_s[rg][t][0] = (float)h + tr0 + tm0 * ry + tm1 * rx;
      coords_s[rg][t][1] = (float)w + tr1 + tm2 * ry + tm3 * rx;
    }
    nofs[rg] = nn * (C_ * HW_);
  }
  __syncthreads();

  // ---- Main loop over 9 taps, pipelined staging ----
  f32x4 acc[5][2] = {};   // [m-tile][o-frag], all indices compile-time
  float cwA[4], cwB[4];
  us8 uA0[4], uA1[4], uB0[4], uB1[4];

  // compute weights + issue 8 corner loads for row R of tap TAP into set S
#define ISSUE(S, R, TAP)                                                       \
  {                                                                            \
    const int r_ = (R);                                                        \
    const int nof = nofs[r_];                                                  \
    const float py = coords_s[r_][TAP][0];                                     \
    const float px = coords_s[r_][TAP][1];                                     \
    const float fy = floorf(py), fx = floorf(px);                              \
    const float wy = py - fy, wx = px - fx;                                    \
    const int y0 = (int)fy, x0 = (int)fx;                                      \
    const int y1 = y0 + 1, x1 = x0 + 1;                                        \
    const float vy0 = (y0 >= 0 && y0 < H_) ? 1.f : 0.f;                        \
    const float vy1 = (y1 >= 0 && y1 < H_) ? 1.f : 0.f;                        \
    const float vx0 = (x0 >= 0 && x0 < W_) ? 1.f : 0.f;                        \
    const float vx1 = (x1 >= 0 && x1 < W_) ? 1.f : 0.f;                        \
    cw##S[0] = (1.f - wy) * (1.f - wx) * vy0 * vx0;                            \
    cw##S[1] = (1.f - wy) * wx * vy0 * vx1;                                    \
    cw##S[2] = wy * (1.f - wx) * vy1 * vx0;                                    \
    cw##S[3] = wy * wx * vy1 * vx1;                                            \
    const int cy0 = min(max(y0, 0), H_ - 1), cy1 = min(max(y1, 0), H_ - 1);    \
    const int cx0 = min(max(x0, 0), W_ - 1), cx1 = min(max(x1, 0), W_ - 1);    \
    const int b0 = nof + (cy0 * W_ + cx0) * C_ + cg * 16;                      \
    const int b1 = nof + (cy0 * W_ + cx1) * C_ + cg * 16;                      \
    const int b2 = nof + (cy1 * W_ + cx0) * C_ + cg * 16;                      \
    const int b3 = nof + (cy1 * W_ + cx1) * C_ + cg * 16;                      \
    u##S##0[0] = *(const us8*)(xt + b0); u##S##1[0] = *(const us8*)(xt + b0 + 8); \
    u##S##0[1] = *(const us8*)(xt + b1); u##S##1[1] = *(const us8*)(xt + b1 + 8); \
    u##S##0[2] = *(const us8*)(xt + b2); u##S##1[2] = *(const us8*)(xt + b2 + 8); \
    u##S##0[3] = *(const us8*)(xt + b3); u##S##1[3] = *(const us8*)(xt + b3 + 8); \
  }

  // lerp set S and write row R into ASB (swizzled slot = (q&24)|((q^R)&7))
#define LERPW(S, R, ASB)                                                       \
  {                                                                            \
    const int r_ = (R);                                                        \
    const f16x2 c0 = hpair(cw##S[0]), c1 = hpair(cw##S[1]);                    \
    const f16x2 c2 = hpair(cw##S[2]), c3 = hpair(cw##S[3]);                    \
    us8 r0v, r1v;                                                              \
    {                                                                          \
      const f16x2* p0 = (const f16x2*)&u##S##0[0];                             \
      const f16x2* p1 = (const f16x2*)&u##S##0[1];                             \
      const f16x2* p2 = (const f16x2*)&u##S##0[2];                             \
      const f16x2* p3 = (const f16x2*)&u##S##0[3];                             \
      f16x2* d = (f16x2*)&r0v;                                                 \
      _Pragma("unroll")                                                        \
      for (int p = 0; p < 4; p++) {                                            \
        f16x2 r = p0[p] * c0; r = p1[p] * c1 + r;                              \
        r = p2[p] * c2 + r;   r = p3[p] * c3 + r;  d[p] = r;                   \
      }                                                                        \
    }                                                                          \
    {                                                                          \
      const f16x2* p0 = (const f16x2*)&u##S##1[0];                             \
      const f16x2* p1 = (const f16x2*)&u##S##1[1];                             \
      const f16x2* p2 = (const f16x2*)&u##S##1[2];                             \
      const f16x2* p3 = (const f16x2*)&u##S##1[3];                             \
      f16x2* d = (f16x2*)&r1v;                                                 \
      _Pragma("unroll")                                                        \
      for (int p = 0; p < 4; p++) {                                            \
        f16x2 r = p0[p] * c0; r = p1[p] * c1 + r;                              \
        r = p2[p] * c2 + r;   r = p3[p] * c3 + r;  d[p] = r;                   \
      }                                                                        \
    }                                                                          \
    const int q0i = cg * 2, q1i = cg * 2 + 1;                                  \
    const int s0 = (q0i & 24) | ((q0i ^ r_) & 7);                              \
    const int s1 = (q1i & 24) | ((q1i ^ r_) & 7);                              \
    *(us8*)(void*)&ASB[r_ * 256 + s0 * 8] = r0v;                               \
    *(us8*)(void*)&ASB[r_ * 256 + s1 * 8] = r1v;                               \
  }

  // One GEMM step: MFMAs on 4-5 A tiles with pair (BX,BY); issue KS+2 pair.
#define GS(KS, BX, BY)                                                         \
  {                                                                            \
    const int q = (KS) * 4 + quad;                                             \
    const int slot = (q & 24) | ((q ^ row) & 7);                               \
    f16x8 a0 = *(const f16x8*)(const void*)&asb[(0 * 16 + row) * 256 + slot * 8]; \
    f16x8 a1 = *(const f16x8*)(const void*)&asb[(1 * 16 + row) * 256 + slot * 8]; \
    f16x8 a2 = *(const f16x8*)(const void*)&asb[(2 * 16 + row) * 256 + slot * 8]; \
    f16x8 a3 = *(const f16x8*)(const void*)&asb[(3 * 16 + row) * 256 + slot * 8]; \
    f16x8 a4;                                                                  \
    if (fat) a4 = *(const f16x8*)(const void*)&asb[(4 * 16 + row) * 256 + slot * 8]; \
    f16x8 nx, ny;                                                              \
    if ((KS) < 6) {                                                            \
      const unsigned short* wfn = wfTap + (size_t)((KS) + 2) * 8192;           \
      nx = *(const f16x8*)(const void*)(wfn);                                  \
      ny = *(const f16x8*)(const void*)(wfn + 512);                            \
    }                                                                          \
    acc[0][0] = __builtin_amdgcn_mfma_f32_16x16x32_f16(a0, BX, acc[0][0], 0, 0, 0); \
    acc[0][1] = __builtin_amdgcn_mfma_f32_16x16x32_f16(a0, BY, acc[0][1], 0, 0, 0); \
    acc[1][0] = __builtin_amdgcn_mfma_f32_16x16x32_f16(a1, BX, acc[1][0], 0, 0, 0); \
    acc[1][1] = __builtin_amdgcn_mfma_f32_16x16x32_f16(a1, BY, acc[1][1], 0, 0, 0); \
    acc[2][0] = __builtin_amdgcn_mfma_f32_16x16x32_f16(a2, BX, acc[2][0], 0, 0, 0); \
    acc[2][1] = __builtin_amdgcn_mfma_f32_16x16x32_f16(a2, BY, acc[2][1], 0, 0, 0); \
    acc[3][0] = __builtin_amdgcn_mfma_f32_16x16x32_f16(a3, BX, acc[3][0], 0, 0, 0); \
    acc[3][1] = __builtin_amdgcn_mfma_f32_16x16x32_f16(a3, BY, acc[3][1], 0, 0, 0); \
    if (fat) {                                                                 \
      acc[4][0] = __builtin_amdgcn_mfma_f32_16x16x32_f16(a4, BX, acc[4][0], 0, 0, 0); \
      acc[4][1] = __builtin_amdgcn_mfma_f32_16x16x32_f16(a4, BY, acc[4][1], 0, 0, 0); \
    }                                                                          \
    if ((KS) < 6) { BX = nx; BY = ny; }                                        \
  }

  const bool third = fat && (sr < 16);  // wave-uniform (sr<16 <=> wave<4)

  // prime the pipeline: corners for (sr, tap 0)
  ISSUE(A, sr, 0);
  __builtin_amdgcn_sched_barrier(0);

  for (int tap = 0; tap < 9; tap++) {
    unsigned short* __restrict__ asb = &As[tap & 1][0];
    const unsigned short* wfTap =
        Wfrag + (size_t)tap * 65536 + wave * 1024 + lane * 8;

    // issue second row's corners + this tap's B pairs (ks0,ks1) BEFORE the
    // lerp: latency hides under lerp VALU; barrier vmcnt drain completes.
    ISSUE(B, sr + 32, tap);
    f16x8 B0 = *(const f16x8*)(const void*)(wfTap);
    f16x8 B1 = *(const f16x8*)(const void*)(wfTap + 512);
    f16x8 B2 = *(const f16x8*)(const void*)(wfTap + 8192);
    f16x8 B3 = *(const f16x8*)(const void*)(wfTap + 8704);
    __builtin_amdgcn_sched_barrier(0);

    LERPW(A, sr, asb);
    if (third) {           // fat third row: reuse set A (its lerp is done)
      ISSUE(A, sr + 64, tap);
      __builtin_amdgcn_sched_barrier(0);
    }
    LERPW(B, sr + 32, asb);
    if (third) LERPW(A, sr + 64, asb);

    __syncthreads();  // ONE barrier per tap (drains all pre-barrier loads)

    if (tap < 8) {    // cross-tap prefetch: hidden under the whole ks loop
      ISSUE(A, sr, tap + 1);
      __builtin_amdgcn_sched_barrier(0);
    }

    GS(0, B0, B1)
    GS(1, B2, B3)
    GS(2, B0, B1)
    GS(3, B2, B3)
    GS(4, B0, B1)
    GS(5, B2, B3)
    GS(6, B0, B1)
    GS(7, B2, B3)
    // NO trailing barrier: As double-buffered; next write to As[tap&1]
    // happens after barrier(tap+1), which orders all reads of As[tap&1].
  }

  // ---- Epilogue: BN + residual + ReLU, per-tile uniform (n, hw) ----
#pragma unroll
  for (int ot = 0; ot < 2; ot++) {
    const int o = wave * 32 + ot * 16 + row;
    const float sc = rsqrtf(var[o] + 1e-5f) * gamma[o];
    const float bi = beta[o] - mean[o] * sc;
#pragma unroll
    for (int t5 = 0; t5 < 5; t5++) {
      if (t5 < nt) {
        const int ts = m0 + t5 * 16;
        const int nn = ts / HW_;
        const int hw0 = ts - nn * HW_ + quad * 4;
        const size_t ob = (size_t)(nn * O_ + o) * HW_ + hw0;
        const f32x4 rv = *(const f32x4*)(xres + ob);
        f32x4 ov;
#pragma unroll
        for (int r = 0; r < 4; r++) ov[r] = fmaxf(acc[t5][ot][r] * sc + bi + rv[r], 0.f);
        *(f32x4*)(out + ob) = ov;
      }
    }
  }
}

extern "C" void kernel_launch(void* const* d_in, const int* in_sizes, int n_in,
                              void* d_out, int out_size, void* d_ws, size_t ws_size,
                              hipStream_t stream) {
  const float* x     = (const float*)d_in[0];
  const float* w_tm  = (const float*)d_in[2];
  const float* b_tm  = (const float*)d_in[3];
  const float* w_tr  = (const float*)d_in[4];
  const float* b_tr  = (const float*)d_in[5];
  const float* w_df  = (const float*)d_in[6];
  const float* gamma = (const float*)d_in[7];
  const float* beta  = (const float*)d_in[8];
  const float* mean  = (const float*)d_in[9];
  const float* var   = (const float*)d_in[10];
  float* out = (float*)d_out;

  char* ws = (char*)d_ws;
  unsigned short* xt    = (unsigned short*)(ws);                       //  9,437,184 B
  unsigned short* wfrag = (unsigned short*)(ws + 9437184);             //  1,179,648 B
  unsigned short* w6p   = (unsigned short*)(ws + 9437184 + 1179648);   //     73,728 B

  k_pre<<<1008, 256, 0, stream>>>(x, w_df, w_tm, w_tr, xt, wfrag, w6p);
  k_fused<<<256, 512, 0, stream>>>(xt, wfrag, w6p, b_tm, b_tr, x,
                                   gamma, beta, mean, var, out);
}